// Round 1
// 1516.538 us; speedup vs baseline: 1.5306x; 1.5306x over previous
//
#include <hip/hip_runtime.h>
#include <math.h>

#define NB 2
#define NC 64
#define NCQ 16
#define ND 96
#define NHW 9216            // 96*96
#define HWD (NHW * ND)      // 884736
#define CHWD (NC * HWD)     // 56623104

// ---- k_energy tiling (unchanged, verified) ----
#define POS_PER_BLOCK 36
#define NCHUNK (NHW / POS_PER_BLOCK)   // 256

// ---- k_out tiling (new) ----
#define OHS 4                    // positions staged per iteration
#define OPOS 72                  // positions per block
#define ONCHUNK (NHW / OPOS)     // 128 chunks per batch -> 256 blocks total
#define OITERS (OPOS / OHS)      // 18
#define NCOL (OHS * ND)          // 384 (p,e) columns per slab

// ---------------------------------------------------------------------------
// Kernel 1: energy[b][d][e] = sum_{cq,hw} q[b,cq,hw,d] * k[b,cq,hw,e]
// (unchanged from previous verified round)
// ---------------------------------------------------------------------------
__global__ __launch_bounds__(256) void k_energy(
    const float* __restrict__ x,
    const float* __restrict__ Wq, const float* __restrict__ bq,
    const float* __restrict__ Wk, const float* __restrict__ bk,
    float* __restrict__ energy)
{
    __shared__ float xs[NC][ND + 1];
    __shared__ float qs[NCQ][ND];
    __shared__ float ks[NCQ][ND];
    __shared__ float Wq_t[NC][NCQ];
    __shared__ float Wk_t[NC][NCQ];

    const int t = threadIdx.x;
    const int b = blockIdx.x / NCHUNK;
    const int chunk = blockIdx.x % NCHUNK;

    for (int idx = t; idx < NC * NCQ; idx += 256) {
        int c = idx / NCQ, cq = idx % NCQ;
        Wq_t[c][cq] = Wq[cq * NC + c];
        Wk_t[c][cq] = Wk[cq * NC + c];
    }

    const int d0 = (t % 16) * 6;
    const int e0 = (t / 16) * 6;
    float acc[6][6];
#pragma unroll
    for (int i = 0; i < 6; ++i)
#pragma unroll
        for (int j = 0; j < 6; ++j) acc[i][j] = 0.f;

    const float* xb = x + b * CHWD;
    const int qk_which = t / 96;
    const int qk_d = t % 96;

    for (int it = 0; it < POS_PER_BLOCK; ++it) {
        const int hw = chunk * POS_PER_BLOCK + it;
        __syncthreads();
        for (int idx = t; idx < NC * ND; idx += 256) {
            int c = idx / ND, dd = idx % ND;
            xs[c][dd] = xb[c * HWD + hw * ND + dd];
        }
        __syncthreads();
        if (t < 192) {
            float a[NCQ];
#pragma unroll
            for (int cq = 0; cq < NCQ; ++cq) a[cq] = 0.f;
            const float(*Wt)[NCQ] = qk_which ? Wk_t : Wq_t;
            for (int c = 0; c < NC; ++c) {
                float xv = xs[c][qk_d];
                const float4* w4 = (const float4*)(&Wt[c][0]);
                float4 w0 = w4[0], w1 = w4[1], w2 = w4[2], w3 = w4[3];
                a[0] = fmaf(w0.x, xv, a[0]);  a[1] = fmaf(w0.y, xv, a[1]);
                a[2] = fmaf(w0.z, xv, a[2]);  a[3] = fmaf(w0.w, xv, a[3]);
                a[4] = fmaf(w1.x, xv, a[4]);  a[5] = fmaf(w1.y, xv, a[5]);
                a[6] = fmaf(w1.z, xv, a[6]);  a[7] = fmaf(w1.w, xv, a[7]);
                a[8] = fmaf(w2.x, xv, a[8]);  a[9] = fmaf(w2.y, xv, a[9]);
                a[10] = fmaf(w2.z, xv, a[10]); a[11] = fmaf(w2.w, xv, a[11]);
                a[12] = fmaf(w3.x, xv, a[12]); a[13] = fmaf(w3.y, xv, a[13]);
                a[14] = fmaf(w3.z, xv, a[14]); a[15] = fmaf(w3.w, xv, a[15]);
            }
            if (qk_which == 0) {
#pragma unroll
                for (int cq = 0; cq < NCQ; ++cq) qs[cq][qk_d] = a[cq] + bq[cq];
            } else {
#pragma unroll
                for (int cq = 0; cq < NCQ; ++cq) ks[cq][qk_d] = a[cq] + bk[cq];
            }
        }
        __syncthreads();
#pragma unroll
        for (int cq = 0; cq < NCQ; ++cq) {
            float qv[6], kv[6];
#pragma unroll
            for (int i = 0; i < 6; ++i) qv[i] = qs[cq][d0 + i];
#pragma unroll
            for (int j = 0; j < 6; ++j) kv[j] = ks[cq][e0 + j];
#pragma unroll
            for (int i = 0; i < 6; ++i)
#pragma unroll
                for (int j = 0; j < 6; ++j)
                    acc[i][j] = fmaf(qv[i], kv[j], acc[i][j]);
        }
    }

    float* eb = energy + b * ND * ND;
#pragma unroll
    for (int i = 0; i < 6; ++i)
#pragma unroll
        for (int j = 0; j < 6; ++j)
            atomicAdd(&eb[(d0 + i) * ND + (e0 + j)], acc[i][j]);
}

// ---------------------------------------------------------------------------
// Kernel 2: softmax over last axis; writes TRANSPOSED attnT[b][e][d]
// ---------------------------------------------------------------------------
__global__ __launch_bounds__(128) void k_softmax(
    const float* __restrict__ energy, float* __restrict__ attnT)
{
    const int row = blockIdx.x;      // b*96 + d
    const int b = row / ND;
    const int d = row % ND;
    const int t = threadIdx.x;
    __shared__ float red[4];

    float v = (t < ND) ? energy[row * ND + t] : -INFINITY;
    float m = v;
#pragma unroll
    for (int o = 32; o > 0; o >>= 1) m = fmaxf(m, __shfl_down(m, o));
    if ((t & 63) == 0) red[t >> 6] = m;
    __syncthreads();
    const float gm = fmaxf(red[0], red[1]);
    float ev = (t < ND) ? __expf(v - gm) : 0.f;
    float s = ev;
#pragma unroll
    for (int o = 32; o > 0; o >>= 1) s += __shfl_down(s, o);
    if ((t & 63) == 0) red[2 + (t >> 6)] = s;
    __syncthreads();
    const float gs = red[2] + red[3];
    if (t < ND) attnT[(b * ND + t) * ND + d] = ev / gs;   // attnT[b][e][d]
}

// ---------------------------------------------------------------------------
// Kernel 3 (rewritten):
//   V[c,hw,e]  = sum_c' Wv[c][c'] x[c',hw,e] + bv[c]      (phase 1)
//   out[c,hw,d]= g * sum_e V[c,hw,e] * attnT[e][d] + x    (phase 2)
// (bias folds exactly because softmax rows sum to 1)
// 512 threads, 4 positions/iter. LDS: XV slab (96K, reused X->V in place),
// attnT (36K), WvT (16K) = 148 KB -> 1 block/CU, 8 waves.
// ---------------------------------------------------------------------------
__global__ __launch_bounds__(512, 1) void k_out(
    const float* __restrict__ x,
    const float* __restrict__ Wv, const float* __restrict__ bv,
    const float* __restrict__ attnT, const float* __restrict__ gamma,
    float* __restrict__ out)
{
    __shared__ float XV[NC * NCOL];   // Xs: [c][col]=c*384+col ; then Vs: [col][c]=col*64+c
    __shared__ float ATs[ND][ND];     // [e][d], stride 96 (=0 mod 32 banks)
    __shared__ float WvT[NC][NC];     // [c'][c]

    const int t = threadIdx.x;
    const int b = blockIdx.x / ONCHUNK;
    const int chunk = blockIdx.x % ONCHUNK;

    const float* xb = x + (size_t)b * CHWD;
    float* ob = (float*)out + (size_t)b * CHWD;
    const float g = gamma[0];

    // one-time staging (ordered before first use by the post-stage barrier)
    {
        const float4* at4 = (const float4*)(attnT + b * ND * ND);
        float4* ats4 = (float4*)(&ATs[0][0]);
        for (int i = t; i < ND * ND / 4; i += 512) ats4[i] = at4[i];
        for (int i = t; i < NC * NC; i += 512) {
            int c = i / NC, cp = i % NC;          // coalesced global read of Wv[c][:]
            WvT[cp][c] = Wv[i];
        }
    }

    // phase-1 mapping: 32 colgrps x 16 cgrps (wave = 4 colgrps x 16 cgrps)
    const int p1_colgrp = t >> 4;
    const int p1_cgrp = t & 15;
    const int p1_col0 = p1_colgrp * 12;
    const int p1_c0 = p1_cgrp * 4;
    const float bvr[4] = {bv[p1_c0], bv[p1_c0 + 1], bv[p1_c0 + 2], bv[p1_c0 + 3]};

    // phase-2 mapping: 64 rgrps x 8 dgrps (wave = 8 rgrps x 8 dgrps, p uniform/wave)
    const int p2_rgrp = t >> 3;             // 0..63
    const int p2_dgrp = t & 7;              // 0..7
    const int p2_p = p2_rgrp >> 4;          // 0..3
    const int p2_c0 = (p2_rgrp & 15) * 4;   // 0..60
    const int p2_d0 = p2_dgrp * 12;         // 0..84

    for (int it = 0; it < OITERS; ++it) {
        const int hw0 = chunk * OPOS + it * OHS;

        __syncthreads();   // prev iter's phase-2 done reading Vs (XV reuse)
        // stage Xs[c][p*96+e] <- x[c][hw0+p][e]; 6144 float4, fully coalesced
#pragma unroll
        for (int k = 0; k < 12; ++k) {
            int idx = t + k * 512;
            int rr = idx / 24, q = idx - rr * 24;   // rr=(c,p) row, q=float4 within row
            int c = rr >> 2, p = rr & 3;
            float4 v = *(const float4*)(xb + (size_t)c * HWD + (size_t)(hw0 + p) * ND + q * 4);
            *(float4*)(XV + c * NCOL + p * ND + q * 4) = v;
        }
        __syncthreads();

        // ---- phase 1: vac[4c][12col] = Wv * X + bv ----
        float vac[4][12];
#pragma unroll
        for (int ci = 0; ci < 4; ++ci)
#pragma unroll
            for (int cj = 0; cj < 12; ++cj) vac[ci][cj] = bvr[ci];

#pragma unroll 2
        for (int cp = 0; cp < NC; ++cp) {
            const float4 w = *(const float4*)(&WvT[cp][p1_c0]);       // 2-way bcast
            const float* xr = XV + cp * NCOL + p1_col0;               // conflict-free
            const float4 x0 = *(const float4*)(xr + 0);
            const float4 x1 = *(const float4*)(xr + 4);
            const float4 x2 = *(const float4*)(xr + 8);
            const float xv[12] = {x0.x, x0.y, x0.z, x0.w,
                                  x1.x, x1.y, x1.z, x1.w,
                                  x2.x, x2.y, x2.z, x2.w};
#pragma unroll
            for (int cj = 0; cj < 12; ++cj) {
                vac[0][cj] = fmaf(w.x, xv[cj], vac[0][cj]);
                vac[1][cj] = fmaf(w.y, xv[cj], vac[1][cj]);
                vac[2][cj] = fmaf(w.z, xv[cj], vac[2][cj]);
                vac[3][cj] = fmaf(w.w, xv[cj], vac[3][cj]);
            }
        }
        __syncthreads();   // all reads of Xs done before in-place overwrite

        // write Vs[col][c] over the same buffer
#pragma unroll
        for (int cj = 0; cj < 12; ++cj) {
            float4 vv = make_float4(vac[0][cj], vac[1][cj], vac[2][cj], vac[3][cj]);
            *(float4*)(XV + (p1_col0 + cj) * NC + p1_c0) = vv;
        }
        __syncthreads();   // Vs ready

        // ---- phase 2: acc[4c][12d] = sum_e Vs[p*96+e][c] * ATs[e][d] ----
        float acc[4][12];
#pragma unroll
        for (int i = 0; i < 4; ++i)
#pragma unroll
            for (int j = 0; j < 12; ++j) acc[i][j] = 0.f;

        const float* vsp = XV + p2_p * ND * NC + p2_c0;
#pragma unroll 2
        for (int e = 0; e < ND; ++e) {
            const float4 vv = *(const float4*)(vsp + e * NC);          // conflict-free
            const float* ar = &ATs[e][p2_d0];                          // conflict-free
            const float4 a0 = *(const float4*)(ar + 0);
            const float4 a1 = *(const float4*)(ar + 4);
            const float4 a2 = *(const float4*)(ar + 8);
            const float av[12] = {a0.x, a0.y, a0.z, a0.w,
                                  a1.x, a1.y, a1.z, a1.w,
                                  a2.x, a2.y, a2.z, a2.w};
            const float vr[4] = {vv.x, vv.y, vv.z, vv.w};
#pragma unroll
            for (int i = 0; i < 4; ++i)
#pragma unroll
                for (int j = 0; j < 12; ++j)
                    acc[i][j] = fmaf(vr[i], av[j], acc[i][j]);
        }

        // epilogue: out = g*acc + x (residual re-read is L1/L2-hot)
        const size_t base = (size_t)(hw0 + p2_p) * ND + p2_d0;
#pragma unroll
        for (int i = 0; i < 4; ++i) {
            const float* xr = xb + (size_t)(p2_c0 + i) * HWD + base;
            float* orow = ob + (size_t)(p2_c0 + i) * HWD + base;
#pragma unroll
            for (int j = 0; j < 12; j += 4) {
                float4 xv = *(const float4*)(xr + j);
                float4 o;
                o.x = fmaf(g, acc[i][j + 0], xv.x);
                o.y = fmaf(g, acc[i][j + 1], xv.y);
                o.z = fmaf(g, acc[i][j + 2], xv.z);
                o.w = fmaf(g, acc[i][j + 3], xv.w);
                *(float4*)(orow + j) = o;
            }
        }
    }
}

// ---------------------------------------------------------------------------
extern "C" void kernel_launch(void* const* d_in, const int* in_sizes, int n_in,
                              void* d_out, int out_size, void* d_ws, size_t ws_size,
                              hipStream_t stream)
{
    const float* x     = (const float*)d_in[0];
    const float* Wq    = (const float*)d_in[1];
    const float* bq    = (const float*)d_in[2];
    const float* Wk    = (const float*)d_in[3];
    const float* bk    = (const float*)d_in[4];
    const float* Wv    = (const float*)d_in[5];
    const float* bv    = (const float*)d_in[6];
    const float* gamma = (const float*)d_in[7];

    float* energy = (float*)d_ws;                  // 2*96*96 floats
    float* attnT  = energy + NB * ND * ND;         // 2*96*96 floats (transposed attn)

    hipMemsetAsync(energy, 0, NB * ND * ND * sizeof(float), stream);
    k_energy<<<NB * NCHUNK, 256, 0, stream>>>(x, Wq, bq, Wk, bk, energy);
    k_softmax<<<NB * ND, 128, 0, stream>>>(energy, attnT);
    k_out<<<NB * ONCHUNK, 512, 0, stream>>>(x, Wv, bv, attnT, gamma, (float*)d_out);
}